// Round 5
// baseline (449.122 us; speedup 1.0000x reference)
//
#include <hip/hip_runtime.h>
#include <math.h>

#define B 64
#define T 2000
#define E 512
#define R 1024
#define A 512
#define M 8

#define NCH 16          // t-chunks for context kernel
#define TCH (T / NCH)   // 125
#define NP  (NCH * 4)   // partials per batch (4 tp-groups per chunk)

typedef float nfloat4 __attribute__((ext_vector_type(4)));

__device__ __forceinline__ float sigmoidf_(float x) { return 1.0f / (1.0f + expf(-x)); }
__device__ __forceinline__ float dot4_(float4 a, float4 b) {
    return (a.x * b.x + a.y * b.y) + (a.z * b.z + a.w * b.w);
}

// Wave64 sum via DPP (VALU-only, no LDS port): row_shr 1/2/4/8 reduce each
// 16-lane row into its lane15; row_bcast15 merges row0->row1 (lane31 =
// rows0+1) ; row_bcast31 merges lane31 into rows 2/3 (lane63 = total).
// Invalid-source lanes contribute old=0. Result broadcast via readlane.
__device__ __forceinline__ float wave_sum64_(float v) {
#define DPPA_(c) v += __int_as_float(__builtin_amdgcn_update_dpp(0, __float_as_int(v), c, 0xf, 0xf, false))
    DPPA_(0x111);  // row_shr:1
    DPPA_(0x112);  // row_shr:2
    DPPA_(0x114);  // row_shr:4
    DPPA_(0x118);  // row_shr:8
    DPPA_(0x142);  // row_bcast:15
    DPPA_(0x143);  // row_bcast:31
#undef DPPA_
    return __int_as_float(__builtin_amdgcn_readlane(__float_as_int(v), 63));
}

// ---------------------------------------------------------------------------
// K1: layer 1, t = tanh(ahs) @ W1^T + b1.  Grid (16 bq, 8 jt), 512 thr.
// Block: 4 batches (b0=bq*4), 64 j (j0=jt*64, 8 j per wave). Lanes span k
// (coalesced 1KB W-row loads); h held in registers; DPP reduce per output.
// Per-CU W traffic: 64 rows * 4KB = 256 KB (vs 4 MB in the fused version).
// ---------------------------------------------------------------------------
__global__ __launch_bounds__(512) void layer1_kernel(
    const float* __restrict__ ahs, const float* __restrict__ W1,
    const float* __restrict__ b1, float* __restrict__ tws)  // tws: [B][A]
{
    __shared__ float4 sh_h[4 * 256];  // [bb][k4]

    const int bq = blockIdx.x, jt = blockIdx.y;
    const int tid = threadIdx.x;
    const int wave = tid >> 6, lane = tid & 63;
    const int b0 = bq * 4;

#pragma unroll
    for (int s = 0; s < 2; ++s) {
        const int idx = tid + s * 512;          // < 1024
        const int bb = idx >> 8, k4 = idx & 255;
        float4 v = ((const float4*)(ahs + (size_t)(b0 + bb) * R))[k4];
        v.x = tanhf(v.x); v.y = tanhf(v.y); v.z = tanhf(v.z); v.w = tanhf(v.w);
        sh_h[idx] = v;
    }
    __syncthreads();

    float4 h4[4][4];
#pragma unroll
    for (int bb = 0; bb < 4; ++bb)
#pragma unroll
        for (int p = 0; p < 4; ++p)
            h4[bb][p] = sh_h[bb * 256 + p * 64 + lane];

    const int jbase = jt * 64 + wave * 8;
#pragma unroll
    for (int jj = 0; jj < 8; ++jj) {
        const int j = jbase + jj;
        const float4* wr = (const float4*)(W1 + (size_t)j * R);
        const float4 w0 = wr[lane], w1 = wr[64 + lane],
                     w2 = wr[128 + lane], w3 = wr[192 + lane];
        const float bias = b1[j];
        float r[4];
#pragma unroll
        for (int bb = 0; bb < 4; ++bb) {
            float acc = (dot4_(h4[bb][0], w0) + dot4_(h4[bb][1], w1)) +
                        (dot4_(h4[bb][2], w2) + dot4_(h4[bb][3], w3));
            r[bb] = wave_sum64_(acc);
        }
        if (lane == 0) {
#pragma unroll
            for (int bb = 0; bb < 4; ++bb)
                tws[(size_t)(b0 + bb) * A + j] = r[bb] + bias;
        }
    }
}

// ---------------------------------------------------------------------------
// K2: layer 2, x = tanh(t @ W2^T).  Same structure, K=512.
// ---------------------------------------------------------------------------
__global__ __launch_bounds__(512) void layer2_kernel(
    const float* __restrict__ tws, const float* __restrict__ W2,
    float* __restrict__ xws)  // xws: [B][A]
{
    __shared__ float4 sh_t[4 * 128];  // [bb][k4]

    const int bq = blockIdx.x, jt = blockIdx.y;
    const int tid = threadIdx.x;
    const int wave = tid >> 6, lane = tid & 63;
    const int b0 = bq * 4;

    {
        const int bb = tid >> 7, k4 = tid & 127;
        sh_t[tid] = ((const float4*)(tws + (size_t)(b0 + bb) * A))[k4];
    }
    __syncthreads();

    float4 t4[4][2];
#pragma unroll
    for (int bb = 0; bb < 4; ++bb)
#pragma unroll
        for (int p = 0; p < 2; ++p)
            t4[bb][p] = sh_t[bb * 128 + p * 64 + lane];

    const int jbase = jt * 64 + wave * 8;
#pragma unroll
    for (int jj = 0; jj < 8; ++jj) {
        const int j = jbase + jj;
        const float4* wr = (const float4*)(W2 + (size_t)j * A);
        const float4 w0 = wr[lane], w1 = wr[64 + lane];
        float r[4];
#pragma unroll
        for (int bb = 0; bb < 4; ++bb) {
            float acc = dot4_(t4[bb][0], w0) + dot4_(t4[bb][1], w1);
            r[bb] = wave_sum64_(acc);
        }
        if (lane == 0) {
#pragma unroll
            for (int bb = 0; bb < 4; ++bb)
                xws[(size_t)(b0 + bb) * A + j] = tanhf(r[bb]);
        }
    }
}

// ---------------------------------------------------------------------------
// K3: head (24-dim linear) + params + alignment + softmax. One block per b.
// Alignment is bounded in [0, M) (z>=0, wmix<1) so exp needs no max-shift.
// ---------------------------------------------------------------------------
__global__ __launch_bounds__(256) void head_align_kernel(
    const float* __restrict__ xws, const float* __restrict__ prev_loc,
    const unsigned char* __restrict__ mask,
    const float* __restrict__ Wlin, const float* __restrict__ blin,
    float* __restrict__ out_w,    // [B][T]
    float* __restrict__ out_loc)  // [B][M]
{
    __shared__ float sh_x[A];
    __shared__ float sh_y[3 * M];
    __shared__ float sh_wmix[M], sh_loc[M], sh_scale[M];
    __shared__ float sred[4];
    __shared__ float sbval;

    const int b = blockIdx.x;
    const int tid = threadIdx.x;
    const int wave = tid >> 6, lane = tid & 63;

    if (tid < 128) ((float4*)sh_x)[tid] = ((const float4*)(xws + (size_t)b * A))[tid];
    __syncthreads();

    // head: 8-lane groups, i = tid>>3 (groups 24..31 idle)
    {
        const int i = tid >> 3, l8 = tid & 7;
        if (i < 3 * M) {
            float s = 0.f;
            for (int k = l8; k < A; k += 8) s += sh_x[k] * Wlin[i * A + k];
            s += __shfl_down(s, 4, 8);
            s += __shfl_down(s, 2, 8);
            s += __shfl_down(s, 1, 8);
            if (l8 == 0) sh_y[i] = s + blin[i];
        }
    }
    __syncthreads();

    if (tid < M) {
        const int m = tid;
        const float delta = sigmoidf_(sh_y[M + m]);
        const float loc = prev_loc[b * M + m] + delta;
        sh_wmix[m]  = sigmoidf_(sh_y[m]);
        sh_loc[m]   = loc;
        sh_scale[m] = sigmoidf_(sh_y[2 * M + m]) * 2.0f + 1.0f;
        out_loc[b * M + m] = loc;
    }
    __syncthreads();

    float a[8];
    float lsum = 0.f;
#pragma unroll
    for (int i = 0; i < 8; ++i) {
        const int t = tid + i * 256;
        if (t < T) {
            const float tf = (float)t;
            float v = 0.f;
#pragma unroll
            for (int m = 0; m < M; ++m) {
                const float d = sh_loc[m] - tf;
                const float s = sh_scale[m];
                v += 0.5f * (erff((d + 0.5f) * s) - erff((d - 0.5f) * s)) * sh_wmix[m];
            }
            if (mask[b * T + t]) v = 0.f;
            a[i] = expf(v);
            lsum += a[i];
        } else {
            a[i] = 0.f;
        }
    }
    const float wsum = wave_sum64_(lsum);
    if (lane == 0) sred[wave] = wsum;
    __syncthreads();
    if (tid == 0) sbval = (sred[0] + sred[1]) + (sred[2] + sred[3]);
    __syncthreads();
    const float inv = 1.0f / sbval;

#pragma unroll
    for (int i = 0; i < 8; ++i) {
        const int t = tid + i * 256;
        if (t < T) out_w[b * T + t] = a[i] * inv;
    }
}

// ---------------------------------------------------------------------------
// Kctx: per-chunk partial context. Grid (B, NCH), 512 threads. Streamed
// nontemporal reads of memory; per-tp-group partials, no in-block reduce.
// ---------------------------------------------------------------------------
__global__ __launch_bounds__(512) void context_partial_kernel(
    const float* __restrict__ memory,
    const float* __restrict__ w,         // [B][T]
    float* __restrict__ partials)        // [B][NCH][4][E]
{
    __shared__ float sh_w[TCH];

    const int b = blockIdx.x;
    const int chunk = blockIdx.y;
    const int tid = threadIdx.x;
    const int t0 = chunk * TCH;

    if (tid < TCH) sh_w[tid] = w[b * T + t0 + tid];
    __syncthreads();

    const int e4 = tid & 127;
    const int tp = tid >> 7;  // 0..3
    const nfloat4* mem4 = (const nfloat4*)(memory + (size_t)(b * T + t0) * E);

    float acc0 = 0.f, acc1 = 0.f, acc2 = 0.f, acc3 = 0.f;
#pragma unroll 4
    for (int t = tp; t < TCH; t += 4) {
        const float wv = sh_w[t];
        const nfloat4 mv = __builtin_nontemporal_load(&mem4[(size_t)t * (E / 4) + e4]);
        acc0 += wv * mv.x;
        acc1 += wv * mv.y;
        acc2 += wv * mv.z;
        acc3 += wv * mv.w;
    }

    nfloat4 accv = {acc0, acc1, acc2, acc3};
    nfloat4* dst = (nfloat4*)(partials + (((size_t)b * NCH + chunk) * 4 + tp) * E);
    dst[e4] = accv;
}

// ---------------------------------------------------------------------------
// Kred: reduce NP=64 partials -> out_ctx [B][E]. float4-vectorized.
// ---------------------------------------------------------------------------
__global__ __launch_bounds__(256) void context_reduce_kernel(
    const float* __restrict__ partials,  // [B][NP][E]
    float* __restrict__ out_ctx)         // [B][E]
{
    const int idx = blockIdx.x * 256 + threadIdx.x;  // < B*E/4
    const int b = idx >> 7;              // / (E/4)
    const int e4 = idx & 127;
    const float4* p = (const float4*)partials + (size_t)b * NP * (E / 4) + e4;
    float4 s = {0.f, 0.f, 0.f, 0.f};
#pragma unroll 8
    for (int c = 0; c < NP; ++c) {
        const float4 v = p[(size_t)c * (E / 4)];
        s.x += v.x; s.y += v.y; s.z += v.z; s.w += v.w;
    }
    ((float4*)out_ctx)[idx] = s;
}

extern "C" void kernel_launch(void* const* d_in, const int* in_sizes, int n_in,
                              void* d_out, int out_size, void* d_ws, size_t ws_size,
                              hipStream_t stream) {
    const float* ahs      = (const float*)d_in[0];
    const float* memory   = (const float*)d_in[1];
    const float* prev_loc = (const float*)d_in[2];
    const unsigned char* mask = (const unsigned char*)d_in[3];
    const float* W1   = (const float*)d_in[4];
    const float* b1   = (const float*)d_in[5];
    const float* W2   = (const float*)d_in[6];
    const float* Wlin = (const float*)d_in[7];
    const float* blin = (const float*)d_in[8];

    float* out = (float*)d_out;
    float* out_ctx = out;                    // [B][E]
    float* out_w   = out + B * E;            // [B][T]
    float* out_loc = out + B * E + B * T;    // [B][M]

    float* partials = (float*)d_ws;                    // [B][NP][E] = 8 MB
    float* tws = partials + (size_t)B * NP * E;        // [B][A] 128 KB
    float* xws = tws + (size_t)B * A;                  // [B][A] 128 KB

    layer1_kernel<<<dim3(16, 8), dim3(512), 0, stream>>>(ahs, W1, b1, tws);
    layer2_kernel<<<dim3(16, 8), dim3(512), 0, stream>>>(tws, W2, xws);
    head_align_kernel<<<dim3(B), dim3(256), 0, stream>>>(
        xws, prev_loc, mask, Wlin, blin, out_w, out_loc);
    context_partial_kernel<<<dim3(B, NCH), dim3(512), 0, stream>>>(
        memory, out_w, partials);
    context_reduce_kernel<<<dim3((B * E / 4) / 256), dim3(256), 0, stream>>>(
        partials, out_ctx);
}